// Round 1
// baseline (65.361 us; speedup 1.0000x reference)
//
#include <hip/hip_runtime.h>

#define NN 384
#define DD 512
#define MARGIN 0.5f
#define EPSV 1e-6f

// R9: fuse out the tail reduce_kernel. Evidence: the top-5 rocprof dispatches
// are ALL the harness's 256 MiB d_ws poison fill (~40 us @ 83-85% of HBM
// peak) -- neither of our kernels makes top-5 (<39.5 us each), so of the
// 60.4 us replay ~40 us is harness reset traffic and only ~15-20 us is ours
// (2 launches + triplet ~5-10 us + the dependent tail reduce). Change: zero
// d_out with a 4-byte memset node, then ONE float atomicAdd per block (384
// adds to one L2 line, ~10-20 ns each, spread over block completions)
// replaces the reduce_kernel launch that had to wait for full kernel
// completion. Unlike R8's fused tail (+4.6 us: 384 threadfence + atomic
// counter + last-block cross-XCD re-read), there is no fence and no reader --
// the atomic RMW IS the communication. Side effect: d_ws is now completely
// unused (free experiment: if the 40 us poison is conditional on ws usage,
// dur_us falls off a cliff; if not, it confirms the ~51 us structural floor).
// Numerics: final sum becomes atomic-order-dependent; bound n*ulp*sum ~ 5e-6.
__global__ __launch_bounds__(512) void triplet_kernel(
    const float* __restrict__ features,
    const int* __restrict__ labels,
    const int* __restrict__ level,
    float* __restrict__ out)
{
    const int i = blockIdx.x;
    const int tid = threadIdx.x;

    __shared__ int   lst[NN];     // [0,np) positives; negatives from the back
    __shared__ float lstd[NN];
    __shared__ int   cnts[2];
    __shared__ float wsum[8];

    if (tid < 2) cnts[tid] = 0;
    __syncthreads();

    // Stage 1: classify columns (threads 0..383), compact via 2 LDS counters.
    if (tid < NN) {
        const int my_label = labels[i];
        const int my_level = level[i];
        const int j = tid;
        if (j != i && labels[j] == my_label) {
            if (level[j] == my_level) {
                lst[atomicAdd(&cnts[0], 1)] = j;          // positive, front
            } else {
                lst[NN - 1 - atomicAdd(&cnts[1], 1)] = j; // negative, back
            }
        }
    }
    __syncthreads();

    const int np = cnts[0], nn = cnts[1];
    const int nlist = np + nn;

    // Stage 2: one 32-lane group per list entry (16 groups, nlist ~11 -> one
    // parallel round); 16 floats/lane over D=512; rows straight from L2.
    const int g  = tid >> 5;
    const int gl = tid & 31;
    const float4* F4 = (const float4*)features;
    const size_t irow = (size_t)i * 128;
    for (int e = g; e < nlist; e += 16) {
        const int j = (e < np) ? lst[e] : lst[NN - 1 - (e - np)];
        const size_t jrow = (size_t)j * 128;
        float acc = 0.f;
#pragma unroll
        for (int r = 0; r < 4; ++r) {
            const int d4 = gl + r * 32;          // coalesced 32 x 16B
            const float4 a = F4[irow + d4];      // same addrs all groups: L1 bcast
            const float4 b = F4[jrow + d4];
            float d;
            d = a.x - b.x + EPSV; acc += d * d;
            d = a.y - b.y + EPSV; acc += d * d;
            d = a.z - b.z + EPSV; acc += d * d;
            d = a.w - b.w + EPSV; acc += d * d;
        }
#pragma unroll
        for (int off = 16; off >= 1; off >>= 1)  // stays inside the 32-group
            acc += __shfl_xor(acc, off, 64);
        if (gl == 0) lstd[e] = sqrtf(acc);
    }
    __syncthreads();

    // Stage 3: hinge over np*nn pairs (~30), block reduce, one atomic.
    const int total = np * nn;
    const int lane = tid & 63, wave = tid >> 6;
    float partial = 0.f;
    for (int p = tid; p < total; p += 512) {
        const int a = p / nn;
        const int b = p - a * nn;
        const float h = lstd[a] - lstd[np + b] + MARGIN;
        partial += (h > 0.f) ? h : 0.f;
    }
#pragma unroll
    for (int off = 32; off >= 1; off >>= 1)
        partial += __shfl_xor(partial, off, 64);
    if (lane == 0) wsum[wave] = partial;
    __syncthreads();
    if (tid == 0 && total > 0) {
        float s = 0.f;
#pragma unroll
        for (int w = 0; w < 8; ++w) s += wsum[w];
        const float v = s / (float)total / (float)NN;
        if (v != 0.f) atomicAdd(out, v);  // out pre-zeroed by memset node
    }
}

extern "C" void kernel_launch(void* const* d_in, const int* in_sizes, int n_in,
                              void* d_out, int out_size, void* d_ws, size_t ws_size,
                              hipStream_t stream) {
    (void)in_sizes; (void)n_in; (void)d_ws; (void)ws_size;
    const float* features = (const float*)d_in[0];
    const int*   labels   = (const int*)d_in[1];
    const int*   level    = (const int*)d_in[2];

    // 4-byte (out_size) memset node: zero the accumulator before the grid adds.
    hipMemsetAsync(d_out, 0, out_size, stream);
    triplet_kernel<<<NN, 512, 0, stream>>>(features, labels, level,
                                           (float*)d_out);
}